// Round 7
// baseline (4995.118 us; speedup 1.0000x reference)
//
#include <hip/hip_runtime.h>
#include <hip/hip_bf16.h>

namespace {
constexpr int B = 16, T = 500, C = 512, KW = 7, NH = 8, HD = 64, HID = 2048;
constexpr int M = B * T;             // 8000 rows, divisible by 64
constexpr float SCALE = 0.125f;      // 1/sqrt(HD)
constexpr int BTC = B * T * C;       // 4,096,000
}

// ---------------- depthwise conv (K=7, pad 3) along T, layout (B,T,C) -------
__global__ __launch_bounds__(256) void dwconv_kernel(
    const float* __restrict__ X, const float* __restrict__ W,
    const float* __restrict__ bias, float* __restrict__ Y) {
  int gid = blockIdx.x * 256 + threadIdx.x;  // 0 .. T*C-1
  int b = blockIdx.y;
  int t = gid >> 9;          // / 512
  int c = gid & 511;
  float acc = bias[c];
  size_t base = (size_t)b * T * C;
#pragma unroll
  for (int k = 0; k < KW; ++k) {
    int tt = t + k - 3;
    if (tt >= 0 && tt < T) acc += X[base + (size_t)tt * C + c] * W[c * KW + k];
  }
  Y[base + gid] = acc;
}

// ---------------- tiled f32 GEMM:  Y[M,N] = X[M,K] @ W[N,K]^T + bias --------
template <bool RELU>
__global__ __launch_bounds__(256) void gemm_kernel(
    const float* __restrict__ X, const float* __restrict__ W,
    const float* __restrict__ bias, float* __restrict__ Y, int N, int Kd) {
  __shared__ __align__(16) float Xs[16][68];
  __shared__ __align__(16) float Ws[16][68];
  const int t = threadIdx.x;
  const int n0 = blockIdx.x * 64;
  const int m0 = blockIdx.y * 64;
  const int tm = t >> 4, tn = t & 15;
  const int r = t >> 2, kq = t & 3;
  const float* xp = X + (size_t)(m0 + r) * Kd + kq * 4;
  const float* wp = W + (size_t)(n0 + r) * Kd + kq * 4;
  float acc[4][4] = {};
  for (int k0 = 0; k0 < Kd; k0 += 16) {
    float4 xv = *(const float4*)(xp + k0);
    float4 wv = *(const float4*)(wp + k0);
    __syncthreads();
    Xs[kq * 4 + 0][r] = xv.x; Xs[kq * 4 + 1][r] = xv.y;
    Xs[kq * 4 + 2][r] = xv.z; Xs[kq * 4 + 3][r] = xv.w;
    Ws[kq * 4 + 0][r] = wv.x; Ws[kq * 4 + 1][r] = wv.y;
    Ws[kq * 4 + 2][r] = wv.z; Ws[kq * 4 + 3][r] = wv.w;
    __syncthreads();
#pragma unroll
    for (int kk = 0; kk < 16; ++kk) {
      float4 a  = *(const float4*)&Xs[kk][tm * 4];
      float4 bb = *(const float4*)&Ws[kk][tn * 4];
      acc[0][0] += a.x * bb.x; acc[0][1] += a.x * bb.y;
      acc[0][2] += a.x * bb.z; acc[0][3] += a.x * bb.w;
      acc[1][0] += a.y * bb.x; acc[1][1] += a.y * bb.y;
      acc[1][2] += a.y * bb.z; acc[1][3] += a.y * bb.w;
      acc[2][0] += a.z * bb.x; acc[2][1] += a.z * bb.y;
      acc[2][2] += a.z * bb.z; acc[2][3] += a.z * bb.w;
      acc[3][0] += a.w * bb.x; acc[3][1] += a.w * bb.y;
      acc[3][2] += a.w * bb.z; acc[3][3] += a.w * bb.w;
    }
  }
#pragma unroll
  for (int i = 0; i < 4; ++i) {
    float4 o;
    o.x = acc[i][0] + bias[n0 + tn * 4 + 0];
    o.y = acc[i][1] + bias[n0 + tn * 4 + 1];
    o.z = acc[i][2] + bias[n0 + tn * 4 + 2];
    o.w = acc[i][3] + bias[n0 + tn * 4 + 3];
    if (RELU) {
      o.x = fmaxf(o.x, 0.f); o.y = fmaxf(o.y, 0.f);
      o.z = fmaxf(o.z, 0.f); o.w = fmaxf(o.w, 0.f);
    }
    *(float4*)&Y[(size_t)(m0 + tm * 4 + i) * N + n0 + tn * 4] = o;
  }
}

// ---------------- row LayerNorm over C=512, one wave per row ----------------
__global__ __launch_bounds__(256) void ln_kernel(
    const float* __restrict__ X, const float* __restrict__ g,
    const float* __restrict__ bta, float* __restrict__ Y) {
  int row = blockIdx.x * 4 + (threadIdx.x >> 6);
  int lane = threadIdx.x & 63;
  const float* x = X + (size_t)row * C;
  float v[8];
  float s = 0.f, ss = 0.f;
#pragma unroll
  for (int i = 0; i < 8; ++i) {
    v[i] = x[lane + i * 64];
    s += v[i];
    ss += v[i] * v[i];
  }
#pragma unroll
  for (int off = 32; off; off >>= 1) {
    s += __shfl_xor(s, off);
    ss += __shfl_xor(ss, off);
  }
  float mean = s * (1.f / C);
  float var = ss * (1.f / C) - mean * mean;
  var = fmaxf(var, 0.f);
  float rstd = rsqrtf(var + 1e-5f);
  float* y = Y + (size_t)row * C;
#pragma unroll
  for (int i = 0; i < 8; ++i) {
    int c = lane + i * 64;
    y[c] = (v[i] - mean) * rstd * g[c] + bta[c];
  }
}

// ---------------- causal flash attention, block = (b, head, 16-query tile) --
__global__ __launch_bounds__(256) void attn_kernel(
    const float* __restrict__ Qg, const float* __restrict__ Kg,
    const float* __restrict__ Vg, float* __restrict__ Yg) {
  __shared__ __align__(16) float Ks[64][65];
  __shared__ __align__(16) float Vs[64][65];
  __shared__ __align__(16) float Qs[16][65];
  __shared__ __align__(16) float Ps[16][65];
  const int tid = threadIdx.x;
  const int lane = tid & 63;
  const int w = tid >> 6;  // wave 0..3, handles queries w*4..w*4+3 of tile
  const int qt = blockIdx.x, hh = blockIdx.y, b = blockIdx.z;
  const int q0 = qt * 16;
  const size_t cbase = (size_t)hh * HD;
#pragma unroll
  for (int i = 0; i < 4; ++i) {
    int qi = w * 4 + i;
    int q = q0 + qi;
    Qs[qi][lane] = (q < T) ? Qg[((size_t)b * T + q) * C + cbase + lane] : 0.f;
  }
  float y[4], mm[4], ll[4];
#pragma unroll
  for (int i = 0; i < 4; ++i) { y[i] = 0.f; mm[i] = -1e30f; ll[i] = 0.f; }
  const int qmax = min(q0 + 15, T - 1);
  for (int key0 = 0; key0 <= qmax; key0 += 64) {
    __syncthreads();
#pragma unroll 4
    for (int rr = 0; rr < 16; ++rr) {
      int row = rr * 4 + w;
      int key = key0 + row;
      bool valid = key < T;
      size_t gidx = ((size_t)b * T + key) * C + cbase + lane;
      Ks[row][lane] = valid ? Kg[gidx] : 0.f;
      Vs[row][lane] = valid ? Vg[gidx] : 0.f;
    }
    __syncthreads();
#pragma unroll
    for (int i = 0; i < 4; ++i) {
      int qi = w * 4 + i;
      int q = q0 + qi;
      if (q >= T || q < key0) continue;  // wave-uniform skip
      float s = 0.f;
#pragma unroll
      for (int d = 0; d < 64; ++d) s += Qs[qi][d] * Ks[lane][d];
      s *= SCALE;
      if (key0 + lane > q) s = -1e30f;  // causal mask (covers key>=T too)
      float mx = s;
#pragma unroll
      for (int off = 32; off; off >>= 1) mx = fmaxf(mx, __shfl_xor(mx, off));
      float mnew = fmaxf(mm[i], mx);
      float alpha = __expf(mm[i] - mnew);  // exp(-1e30)=0 on first chunk
      float p = __expf(s - mnew);
      float ps = p;
#pragma unroll
      for (int off = 32; off; off >>= 1) ps += __shfl_xor(ps, off);
      ll[i] = ll[i] * alpha + ps;
      mm[i] = mnew;
      Ps[qi][lane] = p;  // same-wave write->read, lgkm-ordered
      float acc = y[i] * alpha;
#pragma unroll
      for (int j = 0; j < 64; ++j) acc += Ps[qi][j] * Vs[j][lane];
      y[i] = acc;
    }
  }
#pragma unroll
  for (int i = 0; i < 4; ++i) {
    int qi = w * 4 + i;
    int q = q0 + qi;
    if (q < T) Yg[((size_t)b * T + q) * C + cbase + lane] = y[i] / ll[i];
  }
}

extern "C" void kernel_launch(void* const* d_in, const int* in_sizes, int n_in,
                              void* d_out, int out_size, void* d_ws,
                              size_t ws_size, hipStream_t stream) {
  const float* x     = (const float*)d_in[0];
  const float* dw_w  = (const float*)d_in[1];
  const float* dw_b  = (const float*)d_in[2];
  const float* pw_w  = (const float*)d_in[3];
  const float* pw_b  = (const float*)d_in[4];
  const float* cln_g = (const float*)d_in[5];
  const float* cln_b = (const float*)d_in[6];
  const float* wq    = (const float*)d_in[7];
  const float* bq    = (const float*)d_in[8];
  const float* wk    = (const float*)d_in[9];
  const float* bk    = (const float*)d_in[10];
  const float* wv    = (const float*)d_in[11];
  const float* bv    = (const float*)d_in[12];
  const float* wo    = (const float*)d_in[13];
  const float* bo    = (const float*)d_in[14];
  const float* aln_g = (const float*)d_in[15];
  const float* aln_b = (const float*)d_in[16];
  const float* w1    = (const float*)d_in[17];
  const float* b1    = (const float*)d_in[18];
  const float* w2    = (const float*)d_in[19];
  const float* b2    = (const float*)d_in[20];
  const float* fln_g = (const float*)d_in[21];
  const float* fln_b = (const float*)d_in[22];

  float* ws = (float*)d_ws;
  float* bufA = ws;                    // (B,T,C)
  float* bufB = ws + (size_t)BTC;      // (B,T,C)
  float* bufR = ws + (size_t)2 * BTC;  // (B,T,HID) = 4*BTC; aliases Q,K,V
  float* Qb = bufR;
  float* Kb = bufR + (size_t)BTC;
  float* Vb = bufR + (size_t)2 * BTC;
  float* out = (float*)d_out;          // f32! 3 layer outputs of (B,T,C)

  dim3 blk(256);
  dim3 gemmC(C / 64, M / 64);      // N=512
  dim3 gemmH(HID / 64, M / 64);    // N=2048
  dim3 convG(T * C / 256, B);
  dim3 attnG((T + 15) / 16, NH, B);

  for (int l = 0; l < 3; ++l) {
    float* h = out + (size_t)l * BTC;                       // layer output
    const float* hin = (l == 0) ? x : out + (size_t)(l - 1) * BTC;
    // ---- 2 conv blocks ----
    for (int cb = 0; cb < 2; ++cb) {
      int lc = l * 2 + cb;
      const float* src = (cb == 0) ? hin : h;
      dwconv_kernel<<<convG, blk, 0, stream>>>(src, dw_w + (size_t)lc * C * KW,
                                               dw_b + (size_t)lc * C, bufA);
      gemm_kernel<false><<<gemmC, blk, 0, stream>>>(
          bufA, pw_w + (size_t)lc * C * C, pw_b + (size_t)lc * C, bufB, C, C);
      ln_kernel<<<M / 4, blk, 0, stream>>>(bufB, cln_g + (size_t)lc * C,
                                           cln_b + (size_t)lc * C, h);
    }
    // ---- attention ----
    gemm_kernel<false><<<gemmC, blk, 0, stream>>>(
        h, wq + (size_t)l * C * C, bq + (size_t)l * C, Qb, C, C);
    gemm_kernel<false><<<gemmC, blk, 0, stream>>>(
        h, wk + (size_t)l * C * C, bk + (size_t)l * C, Kb, C, C);
    gemm_kernel<false><<<gemmC, blk, 0, stream>>>(
        h, wv + (size_t)l * C * C, bv + (size_t)l * C, Vb, C, C);
    attn_kernel<<<attnG, blk, 0, stream>>>(Qb, Kb, Vb, bufA);
    gemm_kernel<false><<<gemmC, blk, 0, stream>>>(
        bufA, wo + (size_t)l * C * C, bo + (size_t)l * C, bufB, C, C);
    ln_kernel<<<M / 4, blk, 0, stream>>>(bufB, aln_g + (size_t)l * C,
                                         aln_b + (size_t)l * C, h);
    // ---- FFN ----
    gemm_kernel<true><<<gemmH, blk, 0, stream>>>(
        h, w1 + (size_t)l * HID * C, b1 + (size_t)l * HID, bufR, HID, C);
    gemm_kernel<false><<<gemmC, blk, 0, stream>>>(
        bufR, w2 + (size_t)l * C * HID, b2 + (size_t)l * C, bufA, C, HID);
    ln_kernel<<<M / 4, blk, 0, stream>>>(bufA, fln_g + (size_t)l * C,
                                         fln_b + (size_t)l * C, h);
  }
}

// Round 9
// 3036.157 us; speedup vs baseline: 1.6452x; 1.6452x over previous
//
#include <hip/hip_runtime.h>
#include <hip/hip_bf16.h>

namespace {
constexpr int B = 16, T = 500, C = 512, KW = 7, NH = 8, HD = 64, HID = 2048;
constexpr int M = B * T;             // 8000 rows
constexpr float SCALE = 0.125f;      // 1/sqrt(HD)
constexpr int BTC = B * T * C;       // 4,096,000
// weight arena segment offsets (bf16 element offsets)
constexpr int CC = C * C;                      // 262144
constexpr int SEG_PW0 = 0;
constexpr int SEG_PW1 = CC;
constexpr int SEG_WQ  = 2 * CC;
constexpr int SEG_WK  = 3 * CC;
constexpr int SEG_WV  = 4 * CC;
constexpr int SEG_WO  = 5 * CC;
constexpr int SEG_W1  = 6 * CC;                // 1572864
constexpr int SEG_W2  = 6 * CC + HID * C;     // 2621440
constexpr int SEG_END = 6 * CC + 2 * HID * C; // 3670016
}

typedef short s16x8 __attribute__((ext_vector_type(8)));   // 8 bf16 (4 VGPRs)
typedef float f32x4v __attribute__((ext_vector_type(4)));  // MFMA acc

__device__ __forceinline__ unsigned int bfrne(float f) {  // f32 -> bf16 RNE
  unsigned int u = __float_as_uint(f);
  return (u + 0x7fffu + ((u >> 16) & 1u)) >> 16;
}
__device__ __forceinline__ unsigned int pack2(float a, float b) {
  return bfrne(a) | (bfrne(b) << 16);
}

// ---------------- f32 -> bf16 bulk convert (8 elems/thread) -----------------
__global__ __launch_bounds__(256) void cvtx_kernel(
    const float* __restrict__ X, unsigned short* __restrict__ Y) {
  size_t e = ((size_t)blockIdx.x * 256 + threadIdx.x) * 8;
  float4 a = *(const float4*)(X + e);
  float4 b = *(const float4*)(X + e + 4);
  uint4 o;
  o.x = pack2(a.x, a.y); o.y = pack2(a.z, a.w);
  o.z = pack2(b.x, b.y); o.w = pack2(b.z, b.w);
  *(uint4*)(Y + e) = o;
}

// -------- per-layer weight convert: 8 tensors -> bf16 arena (1 launch) ------
__global__ __launch_bounds__(256) void cvtw_kernel(
    const float* __restrict__ pw0, const float* __restrict__ pw1,
    const float* __restrict__ wqp, const float* __restrict__ wkp,
    const float* __restrict__ wvp, const float* __restrict__ wop,
    const float* __restrict__ w1p, const float* __restrict__ w2p,
    unsigned short* __restrict__ dst) {
  size_t e = ((size_t)blockIdx.x * 256 + threadIdx.x) * 8;
  const float* src;
  size_t off;
  if      (e < SEG_PW1) { src = pw0; off = e - SEG_PW0; }
  else if (e < SEG_WQ)  { src = pw1; off = e - SEG_PW1; }
  else if (e < SEG_WK)  { src = wqp; off = e - SEG_WQ; }
  else if (e < SEG_WV)  { src = wkp; off = e - SEG_WK; }
  else if (e < SEG_WO)  { src = wvp; off = e - SEG_WV; }
  else if (e < SEG_W1)  { src = wop; off = e - SEG_WO; }
  else if (e < SEG_W2)  { src = w1p; off = e - SEG_W1; }
  else                  { src = w2p; off = e - SEG_W2; }
  float4 a = *(const float4*)(src + off);
  float4 b = *(const float4*)(src + off + 4);
  uint4 o;
  o.x = pack2(a.x, a.y); o.y = pack2(a.z, a.w);
  o.z = pack2(b.x, b.y); o.w = pack2(b.z, b.w);
  *(uint4*)(dst + e) = o;
}

// ---------------- MFMA bf16 GEMM: Y[M,N] = X[M,K] @ W[N,K]^T + bias ---------
// 128x128 tile, BK=32, 4 waves of 64x64, register-prefetch staging.
// A-frag: lane holds X[m=lane&15][k=quad*8+j]; B-frag: W[n=lane&15][k=...].
// C/D: col=lane&15, row=quad*4+reg.
template <bool XBF, bool RELU, bool YBF>
__global__ __launch_bounds__(256) void gemm_mfma(
    const void* __restrict__ Xv, const unsigned short* __restrict__ Wb,
    const float* __restrict__ bias, void* __restrict__ Yv, int N, int K) {
  __shared__ unsigned short As[128 * 40];  // row-pad 40 (2-way banks, free)
  __shared__ unsigned short Bs[128 * 40];
  const int tid = threadIdx.x;
  const int n0 = blockIdx.x * 128, m0 = blockIdx.y * 128;
  const int w = tid >> 6, lane = tid & 63;
  const int mh = (w & 1) * 64, nh = (w >> 1) * 64;
  const int quad = lane >> 4, r15 = lane & 15;

  // staging: 2 groups of 8 consecutive k per thread, for A and B tiles
  const int row0 = tid >> 2,           kq0 = (tid & 3) * 8;
  const int row1 = (tid + 256) >> 2,   kq1 = (tid & 3) * 8;
  const int xr0 = min(m0 + row0, M - 1), xr1 = min(m0 + row1, M - 1);
  const int wr0 = n0 + row0, wr1 = n0 + row1;

  f32x4v acc[4][4];
#pragma unroll
  for (int i = 0; i < 4; ++i)
#pragma unroll
    for (int j = 0; j < 4; ++j) acc[i][j] = {0.f, 0.f, 0.f, 0.f};

  auto loadX = [&](int k0, int xr, int kq) -> uint4 {
    if (XBF) {
      return *(const uint4*)((const unsigned short*)Xv + (size_t)xr * K + k0 + kq);
    } else {
      const float* xp = (const float*)Xv + (size_t)xr * K + k0 + kq;
      float4 a = *(const float4*)xp;
      float4 b = *(const float4*)(xp + 4);
      uint4 o;
      o.x = pack2(a.x, a.y); o.y = pack2(a.z, a.w);
      o.z = pack2(b.x, b.y); o.w = pack2(b.z, b.w);
      return o;
    }
  };
  auto loadW = [&](int k0, int wr, int kq) -> uint4 {
    return *(const uint4*)(Wb + (size_t)wr * K + k0 + kq);
  };

  uint4 xv0 = loadX(0, xr0, kq0), xv1 = loadX(0, xr1, kq1);
  uint4 wv0 = loadW(0, wr0, kq0), wv1 = loadW(0, wr1, kq1);
  const int nk = K / 32;
  for (int c = 0; c < nk; ++c) {
    __syncthreads();
    *(uint4*)&As[row0 * 40 + kq0] = xv0;
    *(uint4*)&As[row1 * 40 + kq1] = xv1;
    *(uint4*)&Bs[row0 * 40 + kq0] = wv0;
    *(uint4*)&Bs[row1 * 40 + kq1] = wv1;
    __syncthreads();
    if (c + 1 < nk) {
      int k0 = (c + 1) * 32;
      xv0 = loadX(k0, xr0, kq0); xv1 = loadX(k0, xr1, kq1);
      wv0 = loadW(k0, wr0, kq0); wv1 = loadW(k0, wr1, kq1);
    }
    s16x8 af[4], bg[4];
#pragma unroll
    for (int im = 0; im < 4; ++im)
      af[im] = *(const s16x8*)&As[(mh + im * 16 + r15) * 40 + quad * 8];
#pragma unroll
    for (int in = 0; in < 4; ++in)
      bg[in] = *(const s16x8*)&Bs[(nh + in * 16 + r15) * 40 + quad * 8];
#pragma unroll
    for (int in = 0; in < 4; ++in)
#pragma unroll
      for (int im = 0; im < 4; ++im)
        acc[im][in] = __builtin_amdgcn_mfma_f32_16x16x32_bf16(
            af[im], bg[in], acc[im][in], 0, 0, 0);
  }
  // epilogue
#pragma unroll
  for (int in = 0; in < 4; ++in) {
    int col = n0 + nh + in * 16 + r15;
    float bv = bias[col];
#pragma unroll
    for (int im = 0; im < 4; ++im) {
      int rowb = m0 + mh + im * 16 + quad * 4;
#pragma unroll
      for (int r = 0; r < 4; ++r) {
        int row = rowb + r;
        if (row < M) {
          float v = acc[im][in][r] + bv;
          if (RELU) v = fmaxf(v, 0.f);
          if (YBF)
            ((unsigned short*)Yv)[(size_t)row * N + col] =
                (unsigned short)bfrne(v);
          else
            ((float*)Yv)[(size_t)row * N + col] = v;
        }
      }
    }
  }
}

// ---------------- depthwise conv (K=7, pad 3) along T, layout (B,T,C) -------
__global__ __launch_bounds__(256) void dwconv_kernel(
    const float* __restrict__ X, const float* __restrict__ W,
    const float* __restrict__ bias, float* __restrict__ Y) {
  int gid = blockIdx.x * 256 + threadIdx.x;  // 0 .. T*C-1
  int b = blockIdx.y;
  int t = gid >> 9;
  int c = gid & 511;
  float acc = bias[c];
  size_t base = (size_t)b * T * C;
#pragma unroll
  for (int k = 0; k < KW; ++k) {
    int tt = t + k - 3;
    if (tt >= 0 && tt < T) acc += X[base + (size_t)tt * C + c] * W[c * KW + k];
  }
  Y[base + gid] = acc;
}

// ---------------- row LayerNorm over C=512, one wave per row ----------------
__global__ __launch_bounds__(256) void ln_kernel(
    const float* __restrict__ X, const float* __restrict__ g,
    const float* __restrict__ bta, float* __restrict__ Y) {
  int row = blockIdx.x * 4 + (threadIdx.x >> 6);
  int lane = threadIdx.x & 63;
  const float* x = X + (size_t)row * C;
  float v[8];
  float s = 0.f, ss = 0.f;
#pragma unroll
  for (int i = 0; i < 8; ++i) {
    v[i] = x[lane + i * 64];
    s += v[i];
    ss += v[i] * v[i];
  }
#pragma unroll
  for (int off = 32; off; off >>= 1) {
    s += __shfl_xor(s, off);
    ss += __shfl_xor(ss, off);
  }
  float mean = s * (1.f / C);
  float var = ss * (1.f / C) - mean * mean;
  var = fmaxf(var, 0.f);
  float rstd = rsqrtf(var + 1e-5f);
  float* y = Y + (size_t)row * C;
#pragma unroll
  for (int i = 0; i < 8; ++i) {
    int c = lane + i * 64;
    y[c] = (v[i] - mean) * rstd * g[c] + bta[c];
  }
}

// ---------------- causal flash attention, block = (b, head, 16-query tile) --
__global__ __launch_bounds__(256) void attn_kernel(
    const float* __restrict__ Qg, const float* __restrict__ Kg,
    const float* __restrict__ Vg, float* __restrict__ Yg) {
  __shared__ __align__(16) float Ks[64][65];
  __shared__ __align__(16) float Vs[64][65];
  __shared__ __align__(16) float Qs[16][65];
  __shared__ __align__(16) float Ps[16][65];
  const int tid = threadIdx.x;
  const int lane = tid & 63;
  const int w = tid >> 6;
  const int qt = blockIdx.x, hh = blockIdx.y, b = blockIdx.z;
  const int q0 = qt * 16;
  const size_t cbase = (size_t)hh * HD;
#pragma unroll
  for (int i = 0; i < 4; ++i) {
    int qi = w * 4 + i;
    int q = q0 + qi;
    Qs[qi][lane] = (q < T) ? Qg[((size_t)b * T + q) * C + cbase + lane] : 0.f;
  }
  float y[4], mm[4], ll[4];
#pragma unroll
  for (int i = 0; i < 4; ++i) { y[i] = 0.f; mm[i] = -1e30f; ll[i] = 0.f; }
  const int qmax = min(q0 + 15, T - 1);
  for (int key0 = 0; key0 <= qmax; key0 += 64) {
    __syncthreads();
#pragma unroll 4
    for (int rr = 0; rr < 16; ++rr) {
      int row = rr * 4 + w;
      int key = key0 + row;
      bool valid = key < T;
      size_t gidx = ((size_t)b * T + key) * C + cbase + lane;
      Ks[row][lane] = valid ? Kg[gidx] : 0.f;
      Vs[row][lane] = valid ? Vg[gidx] : 0.f;
    }
    __syncthreads();
#pragma unroll
    for (int i = 0; i < 4; ++i) {
      int qi = w * 4 + i;
      int q = q0 + qi;
      if (q >= T || q < key0) continue;
      float s = 0.f;
#pragma unroll
      for (int d = 0; d < 64; ++d) s += Qs[qi][d] * Ks[lane][d];
      s *= SCALE;
      if (key0 + lane > q) s = -1e30f;
      float mx = s;
#pragma unroll
      for (int off = 32; off; off >>= 1) mx = fmaxf(mx, __shfl_xor(mx, off));
      float mnew = fmaxf(mm[i], mx);
      float alpha = __expf(mm[i] - mnew);
      float p = __expf(s - mnew);
      float ps = p;
#pragma unroll
      for (int off = 32; off; off >>= 1) ps += __shfl_xor(ps, off);
      ll[i] = ll[i] * alpha + ps;
      mm[i] = mnew;
      Ps[qi][lane] = p;
      float acc = y[i] * alpha;
#pragma unroll
      for (int j = 0; j < 64; ++j) acc += Ps[qi][j] * Vs[j][lane];
      y[i] = acc;
    }
  }
#pragma unroll
  for (int i = 0; i < 4; ++i) {
    int qi = w * 4 + i;
    int q = q0 + qi;
    if (q < T) Yg[((size_t)b * T + q) * C + cbase + lane] = y[i] / ll[i];
  }
}

extern "C" void kernel_launch(void* const* d_in, const int* in_sizes, int n_in,
                              void* d_out, int out_size, void* d_ws,
                              size_t ws_size, hipStream_t stream) {
  const float* x     = (const float*)d_in[0];
  const float* dw_w  = (const float*)d_in[1];
  const float* dw_b  = (const float*)d_in[2];
  const float* pw_w  = (const float*)d_in[3];
  const float* pw_b  = (const float*)d_in[4];
  const float* cln_g = (const float*)d_in[5];
  const float* cln_b = (const float*)d_in[6];
  const float* wq    = (const float*)d_in[7];
  const float* bq    = (const float*)d_in[8];
  const float* wk    = (const float*)d_in[9];
  const float* bk    = (const float*)d_in[10];
  const float* wv    = (const float*)d_in[11];
  const float* bv    = (const float*)d_in[12];
  const float* wo    = (const float*)d_in[13];
  const float* bo    = (const float*)d_in[14];
  const float* aln_g = (const float*)d_in[15];
  const float* aln_b = (const float*)d_in[16];
  const float* w1    = (const float*)d_in[17];
  const float* b1    = (const float*)d_in[18];
  const float* w2    = (const float*)d_in[19];
  const float* b2    = (const float*)d_in[20];
  const float* fln_g = (const float*)d_in[21];
  const float* fln_b = (const float*)d_in[22];

  float* ws = (float*)d_ws;
  float* A  = ws;                      // [0,BTC)  f32 scratch
  float* Bf = ws + (size_t)BTC;        // [BTC,2BTC)  xbf slot (as ushort)
  float* R0 = ws + (size_t)2 * BTC;    // Q / GEMM outs
  float* R1 = ws + (size_t)3 * BTC;    // K / ffn1 xbf
  float* R2 = ws + (size_t)4 * BTC;    // V
  unsigned short* WA = (unsigned short*)(ws + (size_t)5 * BTC);  // 7.4 MB
  float* out = (float*)d_out;          // 3 layer outputs, f32

  unsigned short* xbf  = (unsigned short*)Bf;
  unsigned short* fbf  = (unsigned short*)R1;   // ffn1 input bf16
  unsigned short* hbf  = (unsigned short*)A;    // ffn1 output bf16 (spans A,Bf)

  dim3 blk(256);
  dim3 gemmC(C / 128, 63);      // N=512
  dim3 gemmH(HID / 128, 63);    // N=2048
  dim3 convG(T * C / 256, B);
  dim3 attnG((T + 15) / 16, NH, B);
  int cvtxB = BTC / 2048;       // 2000 blocks
  int cvtwB = SEG_END / 2048;   // 1792 blocks

  for (int l = 0; l < 3; ++l) {
    float* h = out + (size_t)l * BTC;
    const float* hin = (l == 0) ? x : out + (size_t)(l - 1) * BTC;
    cvtw_kernel<<<cvtwB, blk, 0, stream>>>(
        pw_w + (size_t)(2 * l) * CC, pw_w + (size_t)(2 * l + 1) * CC,
        wq + (size_t)l * CC, wk + (size_t)l * CC, wv + (size_t)l * CC,
        wo + (size_t)l * CC, w1 + (size_t)l * HID * C,
        w2 + (size_t)l * C * HID, WA);
    // ---- 2 conv blocks ----
    for (int cb = 0; cb < 2; ++cb) {
      int lc = l * 2 + cb;
      const float* src = (cb == 0) ? hin : h;
      dwconv_kernel<<<convG, blk, 0, stream>>>(src, dw_w + (size_t)lc * C * KW,
                                               dw_b + (size_t)lc * C, A);
      cvtx_kernel<<<cvtxB, blk, 0, stream>>>(A, xbf);
      gemm_mfma<true, false, false><<<gemmC, blk, 0, stream>>>(
          xbf, WA + (cb ? SEG_PW1 : SEG_PW0), pw_b + (size_t)lc * C, R0, C, C);
      ln_kernel<<<M / 4, blk, 0, stream>>>(R0, cln_g + (size_t)lc * C,
                                           cln_b + (size_t)lc * C, h);
    }
    // ---- attention ----
    cvtx_kernel<<<cvtxB, blk, 0, stream>>>(h, xbf);
    gemm_mfma<true, false, false><<<gemmC, blk, 0, stream>>>(
        xbf, WA + SEG_WQ, bq + (size_t)l * C, R0, C, C);
    gemm_mfma<true, false, false><<<gemmC, blk, 0, stream>>>(
        xbf, WA + SEG_WK, bk + (size_t)l * C, R1, C, C);
    gemm_mfma<true, false, false><<<gemmC, blk, 0, stream>>>(
        xbf, WA + SEG_WV, bv + (size_t)l * C, R2, C, C);
    attn_kernel<<<attnG, blk, 0, stream>>>(R0, R1, R2, A);
    cvtx_kernel<<<cvtxB, blk, 0, stream>>>(A, xbf);
    gemm_mfma<true, false, false><<<gemmC, blk, 0, stream>>>(
        xbf, WA + SEG_WO, bo + (size_t)l * C, R0, C, C);
    ln_kernel<<<M / 4, blk, 0, stream>>>(R0, aln_g + (size_t)l * C,
                                         aln_b + (size_t)l * C, h);
    // ---- FFN ----
    cvtx_kernel<<<cvtxB, blk, 0, stream>>>(h, fbf);
    gemm_mfma<true, true, true><<<gemmH, blk, 0, stream>>>(
        fbf, WA + SEG_W1, b1 + (size_t)l * HID, hbf, HID, C);
    gemm_mfma<true, false, false><<<gemmC, blk, 0, stream>>>(
        hbf, WA + SEG_W2, b2 + (size_t)l * C, R0, C, HID);
    ln_kernel<<<M / 4, blk, 0, stream>>>(R0, fln_g + (size_t)l * C,
                                         fln_b + (size_t)l * C, h);
  }
}